// Round 8
// baseline (894.031 us; speedup 1.0000x reference)
//
#include <hip/hip_runtime.h>

#define DV   512
#define SV   1024
#define BV   2
#define VV   32000
#define HV   8
#define DFFV 2048
#define NLV  2

typedef __bf16 bf16;
typedef __bf16 bf16x8 __attribute__((ext_vector_type(8)));
typedef float  f32x4  __attribute__((ext_vector_type(4)));

// async global->LDS DMA, 16 B per lane; LDS dest = wave-uniform base + lane*16
__device__ __forceinline__ void lds_dma16(const void* g, void* l) {
  __builtin_amdgcn_global_load_lds(
      (const __attribute__((address_space(1))) unsigned int*)g,
      (__attribute__((address_space(3))) unsigned int*)l,
      16, 0, 0);
}

// ---------------- wave-per-row LayerNorm, D=512 ----------------
template<typename OUT>
__device__ __forceinline__ void row_ln_512(const float* __restrict__ src,
                                           const float* __restrict__ w,
                                           OUT* __restrict__ dst, int lane) {
  const float4 a = *(const float4*)(src + lane*8);
  const float4 b = *(const float4*)(src + lane*8 + 4);
  float s = a.x+a.y+a.z+a.w + b.x+b.y+b.z+b.w;
  float q = a.x*a.x+a.y*a.y+a.z*a.z+a.w*a.w + b.x*b.x+b.y*b.y+b.z*b.z+b.w*b.w;
#pragma unroll
  for (int off = 32; off > 0; off >>= 1) {
    s += __shfl_down(s, off, 64);
    q += __shfl_down(q, off, 64);
  }
  s = __shfl(s, 0, 64); q = __shfl(q, 0, 64);
  const float mu   = s * (1.0f/512.0f);
  const float rstd = rsqrtf(q * (1.0f/512.0f) - mu*mu + 1e-5f);
  const float4 wa = *(const float4*)(w + lane*8);
  const float4 wb = *(const float4*)(w + lane*8 + 4);
  OUT* d = dst + lane*8;
  d[0] = (OUT)((a.x-mu)*rstd*wa.x);
  d[1] = (OUT)((a.y-mu)*rstd*wa.y);
  d[2] = (OUT)((a.z-mu)*rstd*wa.z);
  d[3] = (OUT)((a.w-mu)*rstd*wa.w);
  d[4] = (OUT)((b.x-mu)*rstd*wb.x);
  d[5] = (OUT)((b.y-mu)*rstd*wb.y);
  d[6] = (OUT)((b.z-mu)*rstd*wb.z);
  d[7] = (OUT)((b.w-mu)*rstd*wb.w);
}

__global__ void embed_ln_k(const int* __restrict__ x, const float* __restrict__ wte,
                           const float* __restrict__ w, float* __restrict__ e, int nrows) {
  int row = blockIdx.x * 4 + (threadIdx.x >> 6);
  if (row >= nrows) return;
  int tok = x[row];
  row_ln_512<float>(wte + (long)tok * DV, w, e + (long)row * DV, threadIdx.x & 63);
}

__global__ void rows_ln_f32_k(const float* __restrict__ src, const float* __restrict__ w,
                              float* __restrict__ dst, int nrows) {
  int row = blockIdx.x * 4 + (threadIdx.x >> 6);
  if (row >= nrows) return;
  row_ln_512<float>(src + (long)row * DV, w, dst + (long)row * DV, threadIdx.x & 63);
}

__global__ void rows_ln_bf16_k(const float* __restrict__ src, const float* __restrict__ w,
                               bf16* __restrict__ dst, int nrows) {
  int row = blockIdx.x * 4 + (threadIdx.x >> 6);
  if (row >= nrows) return;
  row_ln_512<bf16>(src + (long)row * DV, w, dst + (long)row * DV, threadIdx.x & 63);
}

__global__ void final_ln_k(const float* __restrict__ f_k, const float* __restrict__ w,
                           float* __restrict__ obuf) {
  int b = threadIdx.x >> 6;
  if (b >= BV) return;
  row_ln_512<float>(f_k + ((long)b * SV + (SV - 1)) * DV, w, obuf + (long)b * DV,
                    threadIdx.x & 63);
}

// ---------------- small prep kernels ----------------
__global__ void cast_f2b_k(const float* __restrict__ in, bf16* __restrict__ o, long n) {
  long i = ((long)blockIdx.x * 256 + threadIdx.x) * 4;
  if (i >= n) return;
  float4 v = *(const float4*)(in + i);
  o[i+0] = (bf16)v.x; o[i+1] = (bf16)v.y; o[i+2] = (bf16)v.z; o[i+3] = (bf16)v.w;
}

__global__ void transpose_f2b_k(const float* __restrict__ in, bf16* __restrict__ o,
                                int R, int C) {
  __shared__ float t[32][33];
  const int c0 = blockIdx.x * 32, r0 = blockIdx.y * 32;
  const int tx = threadIdx.x, ty = threadIdx.y;
#pragma unroll
  for (int k = 0; k < 4; k++) {
    const int rl = ty + k*8;
    t[rl][tx] = in[(long)(r0+rl)*C + c0+tx];
  }
  __syncthreads();
#pragma unroll
  for (int k = 0; k < 4; k++) {
    const int cl = ty + k*8;
    o[(long)(c0+cl)*R + r0+tx] = (bf16)t[tx][cl];
  }
}

__global__ void qk_prep_k(const float* __restrict__ pn, const float* __restrict__ Wq,
                          const float* __restrict__ Wk, bf16* __restrict__ Qh,
                          bf16* __restrict__ Kh) {
  const int s = blockIdx.x, hh = blockIdx.y;
  const int d = threadIdx.x * 4;
  const float4 q  = *(const float4*)(pn + (long)(s+1)*DV + d);
  const float4 kk = *(const float4*)(pn + (long)s*DV + d);
  const float4 aq = *(const float4*)(Wq + (long)hh*DV + d);
  const float4 ak = *(const float4*)(Wk + (long)hh*DV + d);
  const long o = ((long)hh*SV + s)*DV + d;
  Qh[o+0]=(bf16)(q.x*aq.x);  Qh[o+1]=(bf16)(q.y*aq.y);
  Qh[o+2]=(bf16)(q.z*aq.z);  Qh[o+3]=(bf16)(q.w*aq.w);
  Kh[o+0]=(bf16)(kk.x*ak.x); Kh[o+1]=(bf16)(kk.y*ak.y);
  Kh[o+2]=(bf16)(kk.z*ak.z); Kh[o+3]=(bf16)(kk.w*ak.w);
}

// wmean[d] += sum over a 256-row slab of wte  (caller pre-zeros; divide by V at use)
__global__ void wmean_k(const float* __restrict__ wte, float* __restrict__ wm) {
  const int d = blockIdx.x * 256 + threadIdx.x;
  const long v0 = (long)blockIdx.y * 256;
  float acc = 0.f;
  for (int v = 0; v < 256; v++) acc += wte[(v0 + v) * DV + d];
  atomicAdd(&wm[d], acc);
}

// colsum[s] = sum over 250 v-block partials (part layout: [vblk][1024])
__global__ void colsum_reduce_k(const float* __restrict__ part, float* __restrict__ cs) {
  const int s = blockIdx.x * 256 + threadIdx.x;
  float acc = 0.f;
  for (int v = 0; v < VV/128; v++) acc += part[(long)v * SV + s];
  cs[s] = acc;
}

// Vt = e - exw/colsum, written transposed (D,S) bf16
__global__ void vt_transpose_k(const float* __restrict__ e, const float* __restrict__ exw,
                               const float* __restrict__ cs, bf16* __restrict__ VtT) {
  __shared__ float t[32][33];
  const int d0 = blockIdx.x * 32, s0 = blockIdx.y * 32;
  const int tx = threadIdx.x, ty = threadIdx.y;
#pragma unroll
  for (int k = 0; k < 4; k++) {
    const int sl = ty + k*8;
    const float rc = 1.0f / cs[s0 + sl];
    t[sl][tx] = e[(long)(s0+sl)*DV + d0+tx] - exw[(long)(s0+sl)*DV + d0+tx] * rc;
  }
  __syncthreads();
#pragma unroll
  for (int k = 0; k < 4; k++) {
    const int dl = ty + k*8;
    VtT[(long)(d0+dl)*SV + s0+tx] = (bf16)t[tx][dl];
  }
}

// layer-0 variant: ex_wte is the wte column-mean (uniform softmax), exact algebra
__global__ void vt0_transpose_k(const float* __restrict__ e, const float* __restrict__ wm,
                                bf16* __restrict__ VtT) {
  __shared__ float t[32][33];
  const int d0 = blockIdx.x * 32, s0 = blockIdx.y * 32;
  const int tx = threadIdx.x, ty = threadIdx.y;
  const float mval = wm[d0 + tx] * (1.0f / (float)VV);
#pragma unroll
  for (int k = 0; k < 4; k++) {
    const int sl = ty + k*8;
    t[sl][tx] = e[(long)(s0+sl)*DV + d0+tx] - mval;
  }
  __syncthreads();
#pragma unroll
  for (int k = 0; k < 4; k++) {
    const int dl = ty + k*8;
    VtT[(long)(d0+dl)*SV + s0+tx] = (bf16)t[tx][dl];
  }
}

__global__ void logits_k(const float* __restrict__ obuf, const float* __restrict__ wte,
                         float* __restrict__ out, int V) {
  const int wv = threadIdx.x >> 6, lane = threadIdx.x & 63;
  const int v = blockIdx.x * 4 + wv;
  const int b = blockIdx.y;
  const float* o  = obuf + (long)b * DV;
  const float* wr = wte + (long)v * DV;
  const float4 a  = *(const float4*)(wr + lane*8);
  const float4 c  = *(const float4*)(wr + lane*8 + 4);
  const float4 oa = *(const float4*)(o + lane*8);
  const float4 ob = *(const float4*)(o + lane*8 + 4);
  float dt = a.x*oa.x + a.y*oa.y + a.z*oa.z + a.w*oa.w
           + c.x*ob.x + c.y*ob.y + c.z*ob.z + c.w*ob.w;
#pragma unroll
  for (int off = 32; off > 0; off >>= 1) dt += __shfl_down(dt, off, 64);
  if (lane == 0) out[(long)b * V + v] = dt;
}

// ---------------- m97-style NT MFMA GEMM: C[m,n] = sum_k A[m,k]*B[n,k] ----------------
// 128x128x32 tile, unpadded LDS, global_load_lds width-16 staging.
// EPI: 1=atomicAdd f32 (split-K), 2=store bf16,
//      3=causal mask * wn[m]*scale -> bf16 (krn build; fully-masked tiles skipped —
//        consumer's K-truncation provably never reads them),
//      4=gelu -> bf16,
//      5=exp -> bf16 + per-block partial row-sums into Cf[vblk*SV + s] (spread, low-contention)
// BSRC: 0 = B bf16 (DMA), 1 = B f32 (VALU convert during staging)
struct GemmArgs {
  const bf16* A; const bf16* B; const float* Bf32;
  float* Cf; bf16* Cb;
  int K, lda, ldb, ldc;
  long sAh, sAb, sBh, sBb, sCh, sCb;
  int Hmod, KC, causal, swap;
  float scale;
};

template<int EPI, int BSRC>
__global__ __launch_bounds__(256)
void gemm_nt(GemmArgs g) {
  __shared__ bf16 As[128][32];
  __shared__ bf16 Bs[128][32];
  const int tid = threadIdx.x;
  const int z = blockIdx.z;
  const int chunk = z % g.KC;
  const int zo = z / g.KC;
  const int h = zo % g.Hmod;
  const int b = zo / g.Hmod;
  int bx = blockIdx.x, by = blockIdx.y;
  if (g.swap) { int t = bx; bx = by; by = t; }
  const int m0 = by * 128;
  const int n0 = bx * 128;
  const long coff = (long)h * g.sCh + (long)b * g.sCb;

  if (EPI == 3 && n0 > m0 + 127) return;  // fully-masked krn tile: never read downstream

  const bf16* A = g.A + (long)h * g.sAh + (long)b * g.sAb;
  const bf16* B = nullptr;
  const float* Bf = nullptr;
  if constexpr (BSRC == 0) B  = g.B + (long)h * g.sBh + (long)b * g.sBb;
  else                     Bf = g.Bf32 + (long)h * g.sBh + (long)b * g.sBb;
  const int lane = tid & 63;
  const int wv = tid >> 6;
  const int wm = (wv >> 1) * 64;
  const int wn = (wv & 1) * 64;
  const int frow = lane & 15;
  const int quad = lane >> 4;
  // DMA staging: wave wv covers rows wv*16 + c*64 .. +15; lane -> (row, 16B chunk)
  const int drow = lane >> 2;
  const int dcol = (lane & 3) * 8;
  // VALU staging (BSRC=1 B path)
  const int sr = tid >> 2;
  const int sc = (tid & 3) * 8;

  const f32x4 fzero = {0.f, 0.f, 0.f, 0.f};
  f32x4 acc[4][4];
#pragma unroll
  for (int i = 0; i < 4; i++)
#pragma unroll
    for (int j = 0; j < 4; j++) acc[i][j] = fzero;

  int k0, klen;
  if (g.causal) { k0 = 0; klen = min(g.K, m0 + 128); }
  else          { klen = g.K / g.KC; k0 = chunk * klen; }

  for (int kt = 0; kt < klen; kt += 32) {
    const int kk = k0 + kt;
#pragma unroll
    for (int c = 0; c < 2; c++) {
      const int rr = c*64 + wv*16;
      lds_dma16(A + (long)(m0 + rr + drow) * g.lda + kk + dcol, &As[rr][0]);
    }
    if constexpr (BSRC == 0) {
#pragma unroll
      for (int c = 0; c < 2; c++) {
        const int rr = c*64 + wv*16;
        lds_dma16(B + (long)(n0 + rr + drow) * g.ldb + kk + dcol, &Bs[rr][0]);
      }
    } else {
#pragma unroll
      for (int i = 0; i < 2; i++) {
        const int r = sr + i*64;
        const float* bp = Bf + (long)(n0 + r) * g.ldb + kk + sc;
        const float4 u0 = *(const float4*)bp;
        const float4 u1 = *(const float4*)(bp + 4);
        bf16x8 t;
        t[0]=(bf16)u0.x; t[1]=(bf16)u0.y; t[2]=(bf16)u0.z; t[3]=(bf16)u0.w;
        t[4]=(bf16)u1.x; t[5]=(bf16)u1.y; t[6]=(bf16)u1.z; t[7]=(bf16)u1.w;
        *(bf16x8*)(&Bs[r][sc]) = t;
      }
    }
    __syncthreads();
    bf16x8 af[4], bfr[4];
#pragma unroll
    for (int i = 0; i < 4; i++)
      af[i] = *(const bf16x8*)(&As[wm + i*16 + frow][quad*8]);
#pragma unroll
    for (int j = 0; j < 4; j++)
      bfr[j] = *(const bf16x8*)(&Bs[wn + j*16 + frow][quad*8]);
#pragma unroll
    for (int i = 0; i < 4; i++)
#pragma unroll
      for (int j = 0; j < 4; j++)
        acc[i][j] = __builtin_amdgcn_mfma_f32_16x16x32_bf16(af[i], bfr[j], acc[i][j], 0, 0, 0);
    __syncthreads();
  }

  const int rb = quad * 4;
  if (EPI == 5) {
    // exp store + per-block partial colsum into Cf[vblk*SV + gm]
    const int vblk = n0 >> 7;
#pragma unroll
    for (int i = 0; i < 4; i++) {
#pragma unroll
      for (int r = 0; r < 4; r++) {
        const int gm = m0 + wm + i*16 + rb + r;
        float rs = 0.f;
#pragma unroll
        for (int j = 0; j < 4; j++) {
          const int gn = n0 + wn + j*16 + frow;
          const float ev = __expf(acc[i][j][r]);
          g.Cb[(long)gm * g.ldc + gn] = (bf16)ev;
          rs += ev;
        }
#pragma unroll
        for (int off = 1; off < 16; off <<= 1)
          rs += __shfl_xor(rs, off, 64);
        if (frow == 0) atomicAdd(g.Cf + (long)vblk * SV + gm, rs);
      }
    }
  } else {
#pragma unroll
    for (int i = 0; i < 4; i++) {
#pragma unroll
      for (int j = 0; j < 4; j++) {
#pragma unroll
        for (int r = 0; r < 4; r++) {
          const int gm = m0 + wm + i*16 + rb + r;
          const int gn = n0 + wn + j*16 + frow;
          const float v = acc[i][j][r];
          const long off = coff + (long)gm * g.ldc + gn;
          if (EPI == 1) {
            atomicAdd(g.Cf + off, v);
          } else if (EPI == 2) {
            g.Cb[off] = (bf16)v;
          } else if (EPI == 3) {
            const float val = (gn <= gm) ? v * g.scale / (float)(gm + 1) : 0.0f;
            g.Cb[off] = (bf16)val;
          } else if (EPI == 4) {
            const float ge = 0.5f * v * (1.0f + erff(v * 0.70710678118f));
            g.Cb[off] = (bf16)ge;
          }
        }
      }
    }
  }
}

// shared tail for each layer: U_rs -> Wo -> LN -> MLP (-> optional f_k cast)
static void layer_tail(int il, bf16* krn, bf16* VtT, bf16* U_rs, bf16* Wo_b,
                       float* f_k, bf16* f_k_b, bf16* hbuf, bf16* Gbuf,
                       bf16* w1_b, bf16* w2_b, const float* lnmw, int do_cast,
                       hipStream_t stream) {
  { // U_rs[b][s, h*D+d] = sum_t krn[h,s,t] * Vt[b,t,d]  (causal K-truncation)
    GemmArgs g = {};
    g.A = krn; g.B = VtT; g.Cb = U_rs;
    g.K = SV; g.lda = SV; g.ldb = SV; g.ldc = HV*DV;
    g.sAh = (long)SV*SV; g.sBb = (long)DV*SV;
    g.sCh = DV; g.sCb = (long)SV*HV*DV;
    g.Hmod = HV; g.KC = 1; g.causal = 1;
    gemm_nt<2,0><<<dim3(DV/128, SV/128, BV*HV), 256, 0, stream>>>(g);
  }
  { // f_k += U_rs @ Wo[il]^T   (split-K=8, atomic)
    GemmArgs g = {};
    g.A = U_rs; g.B = Wo_b + (long)il*DV*HV*DV; g.Cf = f_k;
    g.K = HV*DV; g.lda = HV*DV; g.ldb = HV*DV; g.ldc = DV;
    g.sAb = (long)SV*HV*DV; g.sCb = (long)SV*DV;
    g.Hmod = 1; g.KC = 8; g.causal = 0;
    gemm_nt<1,0><<<dim3(DV/128, SV/128, BV*8), 256, 0, stream>>>(g);
  }
  rows_ln_bf16_k<<<dim3(BV*SV/4), 256, 0, stream>>>(f_k, lnmw, hbuf, BV*SV);
  { // Gbuf = gelu(h @ w1^T)
    GemmArgs g = {};
    g.A = hbuf; g.B = w1_b; g.Cb = Gbuf;
    g.K = DV; g.lda = DV; g.ldb = DV; g.ldc = DFFV;
    g.sAb = (long)SV*DV; g.sCb = (long)SV*DFFV;
    g.Hmod = 1; g.KC = 1; g.causal = 0;
    gemm_nt<4,0><<<dim3(DFFV/128, SV/128, BV), 256, 0, stream>>>(g);
  }
  { // f_k += Gbuf @ w2^T   (split-K=8, atomic)
    GemmArgs g = {};
    g.A = Gbuf; g.B = w2_b; g.Cf = f_k;
    g.K = DFFV; g.lda = DFFV; g.ldb = DFFV; g.ldc = DV;
    g.sAb = (long)SV*DFFV; g.sCb = (long)SV*DV;
    g.Hmod = 1; g.KC = 8; g.causal = 0;
    gemm_nt<1,0><<<dim3(DV/128, SV/128, BV*8), 256, 0, stream>>>(g);
  }
  if (do_cast)
    cast_f2b_k<<<dim3((BV*SV*DV/4+255)/256), 256, 0, stream>>>(f_k, f_k_b, (long)BV*SV*DV);
}

extern "C" void kernel_launch(void* const* d_in, const int* in_sizes, int n_in,
                              void* d_out, int out_size, void* d_ws, size_t ws_size,
                              hipStream_t stream) {
  const int*   x    = (const int*)d_in[0];
  const float* wte  = (const float*)d_in[1];
  const float* wpe  = (const float*)d_in[2];
  const float* lnew = (const float*)d_in[3];
  const float* lnpw = (const float*)d_in[4];
  const float* lnfw = (const float*)d_in[5];
  const float* lnmw = (const float*)d_in[6];
  const float* Wq   = (const float*)d_in[7];
  const float* Wk   = (const float*)d_in[8];
  const float* Wo   = (const float*)d_in[9];
  const float* w1   = (const float*)d_in[10];
  const float* w2   = (const float*)d_in[11];
  float* out = (float*)d_out;
  (void)in_sizes; (void)n_in; (void)out_size; (void)ws_size;

  char* p = (char*)d_ws;
  auto alloc = [&](size_t bytes) -> void* {
    void* r = (void*)p;
    p += (bytes + 255) & ~(size_t)255;
    return r;
  };
  // persistent buffers (~117 MB)
  float* e      = (float*)alloc((size_t)BV*SV*DV*4);
  float* pn     = (float*)alloc((size_t)(SV+1)*DV*4);
  bf16*  wteT_b = (bf16*)alloc((size_t)DV*VV*2);
  bf16*  wte_b  = (bf16*)alloc((size_t)VV*DV*2);
  bf16*  krn    = (bf16*)alloc((size_t)HV*SV*SV*2);
  bf16*  Wo_b   = (bf16*)alloc((size_t)NLV*DV*HV*DV*2);
  bf16*  w1_b   = (bf16*)alloc((size_t)DFFV*DV*2);
  bf16*  w2_b   = (bf16*)alloc((size_t)DV*DFFV*2);
  float* f_k    = (float*)alloc((size_t)BV*SV*DV*4);
  bf16*  f_k_b  = (bf16*)alloc((size_t)BV*SV*DV*2);
  float* exw    = (float*)alloc((size_t)SV*DV*4);
  bf16*  VtT    = (bf16*)alloc((size_t)BV*DV*SV*2);
  bf16*  hbuf   = (bf16*)alloc((size_t)BV*SV*DV*2);
  float* colsum = (float*)alloc((size_t)SV*4);
  float* part   = (float*)alloc((size_t)(VV/128)*SV*4);   // 1 MB partial colsums
  float* obuf   = (float*)alloc((size_t)BV*DV*4);
  float* wmean  = (float*)alloc((size_t)DV*4);
  // arena (65.5 MB), time-sliced: {Qh,Kh} -> {U_rs,Gbuf}(L0) -> PT(L1) -> {U_rs,Gbuf}(L1)
  char*  arena  = (char*)alloc((size_t)SV*VV*2);
  bf16*  Qh     = (bf16*)arena;
  bf16*  Kh     = (bf16*)(arena + (size_t)HV*SV*DV*2);
  bf16*  PT     = (bf16*)arena;                          // (S,V) unnormalized probs
  bf16*  U_rs   = (bf16*)arena;                          // (B,S,H*D)
  bf16*  Gbuf   = (bf16*)(arena + (size_t)BV*SV*HV*DV*2);// (B,S,DFF)

  // ---- prologue ----
  hipMemsetAsync(f_k,   0, (size_t)BV*SV*DV*4, stream);
  hipMemsetAsync(f_k_b, 0, (size_t)BV*SV*DV*2, stream);
  hipMemsetAsync(wmean, 0, (size_t)DV*4, stream);
  wmean_k<<<dim3(DV/256, VV/256), 256, 0, stream>>>(wte, wmean);
  transpose_f2b_k<<<dim3(DV/32, VV/32), dim3(32,8), 0, stream>>>(wte, wteT_b, VV, DV);
  cast_f2b_k<<<dim3((VV*DV/4+255)/256), 256, 0, stream>>>(wte, wte_b, (long)VV*DV);
  cast_f2b_k<<<dim3((NLV*DV*HV*DV/4+255)/256), 256, 0, stream>>>(Wo, Wo_b, (long)NLV*DV*HV*DV);
  cast_f2b_k<<<dim3((DFFV*DV/4+255)/256), 256, 0, stream>>>(w1, w1_b, (long)DFFV*DV);
  cast_f2b_k<<<dim3((DV*DFFV/4+255)/256), 256, 0, stream>>>(w2, w2_b, (long)DV*DFFV);
  embed_ln_k<<<dim3(BV*SV/4), 256, 0, stream>>>(x, wte, lnew, e, BV*SV);
  rows_ln_f32_k<<<dim3((SV+1+3)/4), 256, 0, stream>>>(wpe, lnpw, pn, SV+1);
  qk_prep_k<<<dim3(SV, HV), 128, 0, stream>>>(pn, Wq, Wk, Qh, Kh);

  { // krn[h,s,t] = mask(t<=s) * (Q.K)/sqrt(D) * wn[s]  -> bf16 (masked tiles skipped)
    GemmArgs g = {};
    g.A = Qh; g.B = Kh; g.Cb = krn;
    g.K = DV; g.lda = DV; g.ldb = DV; g.ldc = SV;
    g.sAh = (long)SV*DV; g.sBh = (long)SV*DV; g.sCh = (long)SV*SV;
    g.Hmod = HV; g.KC = 1; g.causal = 0;
    g.scale = 0.044194173824159216f;  // 1/sqrt(512)
    gemm_nt<3,0><<<dim3(SV/128, SV/128, HV), 256, 0, stream>>>(g);
  }

  // ---- layer 0: f_k==0 => R uniform => ex_wte/sumR == mean_v(wte) (exact) ----
  for (int b = 0; b < BV; b++)
    vt0_transpose_k<<<dim3(DV/32, SV/32), dim3(32,8), 0, stream>>>(
        e + (long)b*SV*DV, wmean, VtT + (long)b*DV*SV);
  layer_tail(0, krn, VtT, U_rs, Wo_b, f_k, f_k_b, hbuf, Gbuf, w1_b, w2_b, lnmw, 1, stream);

  // ---- layer 1: PT = exp(f_k@wte^T); per-v Z and max-shift drop out of exw/colsum ----
  for (int b = 0; b < BV; b++) {
    hipMemsetAsync(part, 0, (size_t)(VV/128)*SV*4, stream);
    { // PT(S,V) = exp(logits), fused partial colsum into part
      GemmArgs g = {};
      g.A = f_k_b + (long)b*SV*DV; g.B = wte_b; g.Cb = PT; g.Cf = part;
      g.K = DV; g.lda = DV; g.ldb = DV; g.ldc = VV;
      g.Hmod = 1; g.KC = 1; g.causal = 0; g.swap = 1;
      gemm_nt<5,0><<<dim3(SV/128, VV/128, 1), 256, 0, stream>>>(g);
    }
    colsum_reduce_k<<<dim3(SV/256), 256, 0, stream>>>(part, colsum);
    hipMemsetAsync(exw, 0, (size_t)SV*DV*4, stream);
    { // exw(S,D) = P'^T @ wte  (split-K=25 over V, atomic)
      GemmArgs g = {};
      g.A = PT; g.B = wteT_b; g.Cf = exw;
      g.K = VV; g.lda = VV; g.ldb = VV; g.ldc = DV;
      g.Hmod = 1; g.KC = 25; g.causal = 0;
      gemm_nt<1,0><<<dim3(DV/128, SV/128, 25), 256, 0, stream>>>(g);
    }
    vt_transpose_k<<<dim3(DV/32, SV/32), dim3(32,8), 0, stream>>>(
        e + (long)b*SV*DV, exw, colsum, VtT + (long)b*DV*SV);
  }
  layer_tail(1, krn, VtT, U_rs, Wo_b, f_k, f_k_b, hbuf, Gbuf, w1_b, w2_b, lnmw, 0, stream);

  final_ln_k<<<1, 256, 0, stream>>>(f_k, lnfw, obuf);
  logits_k<<<dim3(VV/4, BV), 256, 0, stream>>>(obuf, wte, out, VV);
}

// Round 9
// 764.768 us; speedup vs baseline: 1.1690x; 1.1690x over previous
//
#include <hip/hip_runtime.h>

#define DV   512
#define SV   1024
#define BV   2
#define VV   32000
#define HV   8
#define DFFV 2048
#define NLV  2
#define KCX  20   // exw split-K chunks

typedef __bf16 bf16;
typedef __bf16 bf16x8 __attribute__((ext_vector_type(8)));
typedef float  f32x4  __attribute__((ext_vector_type(4)));

// async global->LDS DMA, 16 B per lane; LDS dest = wave-uniform base + lane*16
__device__ __forceinline__ void lds_dma16(const void* g, void* l) {
  __builtin_amdgcn_global_load_lds(
      (const __attribute__((address_space(1))) unsigned int*)g,
      (__attribute__((address_space(3))) unsigned int*)l,
      16, 0, 0);
}

// ---------------- wave-per-row LayerNorm, D=512 ----------------
template<typename OUT>
__device__ __forceinline__ void row_ln_512(const float* __restrict__ src,
                                           const float* __restrict__ w,
                                           OUT* __restrict__ dst, int lane) {
  const float4 a = *(const float4*)(src + lane*8);
  const float4 b = *(const float4*)(src + lane*8 + 4);
  float s = a.x+a.y+a.z+a.w + b.x+b.y+b.z+b.w;
  float q = a.x*a.x+a.y*a.y+a.z*a.z+a.w*a.w + b.x*b.x+b.y*b.y+b.z*b.z+b.w*b.w;
#pragma unroll
  for (int off = 32; off > 0; off >>= 1) {
    s += __shfl_down(s, off, 64);
    q += __shfl_down(q, off, 64);
  }
  s = __shfl(s, 0, 64); q = __shfl(q, 0, 64);
  const float mu   = s * (1.0f/512.0f);
  const float rstd = rsqrtf(q * (1.0f/512.0f) - mu*mu + 1e-5f);
  const float4 wa = *(const float4*)(w + lane*8);
  const float4 wb = *(const float4*)(w + lane*8 + 4);
  OUT* d = dst + lane*8;
  d[0] = (OUT)((a.x-mu)*rstd*wa.x);
  d[1] = (OUT)((a.y-mu)*rstd*wa.y);
  d[2] = (OUT)((a.z-mu)*rstd*wa.z);
  d[3] = (OUT)((a.w-mu)*rstd*wa.w);
  d[4] = (OUT)((b.x-mu)*rstd*wb.x);
  d[5] = (OUT)((b.y-mu)*rstd*wb.y);
  d[6] = (OUT)((b.z-mu)*rstd*wb.z);
  d[7] = (OUT)((b.w-mu)*rstd*wb.w);
}

__global__ void embed_ln_k(const int* __restrict__ x, const float* __restrict__ wte,
                           const float* __restrict__ w, float* __restrict__ e, int nrows) {
  int row = blockIdx.x * 4 + (threadIdx.x >> 6);
  if (row >= nrows) return;
  int tok = x[row];
  row_ln_512<float>(wte + (long)tok * DV, w, e + (long)row * DV, threadIdx.x & 63);
}

__global__ void rows_ln_f32_k(const float* __restrict__ src, const float* __restrict__ w,
                              float* __restrict__ dst, int nrows) {
  int row = blockIdx.x * 4 + (threadIdx.x >> 6);
  if (row >= nrows) return;
  row_ln_512<float>(src + (long)row * DV, w, dst + (long)row * DV, threadIdx.x & 63);
}

__global__ void rows_ln_bf16_k(const float* __restrict__ src, const float* __restrict__ w,
                               bf16* __restrict__ dst, int nrows) {
  int row = blockIdx.x * 4 + (threadIdx.x >> 6);
  if (row >= nrows) return;
  row_ln_512<bf16>(src + (long)row * DV, w, dst + (long)row * DV, threadIdx.x & 63);
}

__global__ void final_ln_k(const float* __restrict__ f_k, const float* __restrict__ w,
                           float* __restrict__ obuf) {
  int b = threadIdx.x >> 6;
  if (b >= BV) return;
  row_ln_512<float>(f_k + ((long)b * SV + (SV - 1)) * DV, w, obuf + (long)b * DV,
                    threadIdx.x & 63);
}

// ---------------- small prep kernels ----------------
__global__ void cast_f2b_k(const float* __restrict__ in, bf16* __restrict__ o, long n) {
  long i = ((long)blockIdx.x * 256 + threadIdx.x) * 4;
  if (i >= n) return;
  float4 v = *(const float4*)(in + i);
  o[i+0] = (bf16)v.x; o[i+1] = (bf16)v.y; o[i+2] = (bf16)v.z; o[i+3] = (bf16)v.w;
}

__global__ void transpose_f2b_k(const float* __restrict__ in, bf16* __restrict__ o,
                                int R, int C) {
  __shared__ float t[32][33];
  const int c0 = blockIdx.x * 32, r0 = blockIdx.y * 32;
  const int tx = threadIdx.x, ty = threadIdx.y;
#pragma unroll
  for (int k = 0; k < 4; k++) {
    const int rl = ty + k*8;
    t[rl][tx] = in[(long)(r0+rl)*C + c0+tx];
  }
  __syncthreads();
#pragma unroll
  for (int k = 0; k < 4; k++) {
    const int cl = ty + k*8;
    o[(long)(c0+cl)*R + r0+tx] = (bf16)t[tx][cl];
  }
}

__global__ void qk_prep_k(const float* __restrict__ pn, const float* __restrict__ Wq,
                          const float* __restrict__ Wk, bf16* __restrict__ Qh,
                          bf16* __restrict__ Kh) {
  const int s = blockIdx.x, hh = blockIdx.y;
  const int d = threadIdx.x * 4;
  const float4 q  = *(const float4*)(pn + (long)(s+1)*DV + d);
  const float4 kk = *(const float4*)(pn + (long)s*DV + d);
  const float4 aq = *(const float4*)(Wq + (long)hh*DV + d);
  const float4 ak = *(const float4*)(Wk + (long)hh*DV + d);
  const long o = ((long)hh*SV + s)*DV + d;
  Qh[o+0]=(bf16)(q.x*aq.x);  Qh[o+1]=(bf16)(q.y*aq.y);
  Qh[o+2]=(bf16)(q.z*aq.z);  Qh[o+3]=(bf16)(q.w*aq.w);
  Kh[o+0]=(bf16)(kk.x*ak.x); Kh[o+1]=(bf16)(kk.y*ak.y);
  Kh[o+2]=(bf16)(kk.z*ak.z); Kh[o+3]=(bf16)(kk.w*ak.w);
}

// wmean[d] += sum over a 256-row slab of wte  (caller pre-zeros; divide by V at use)
__global__ void wmean_k(const float* __restrict__ wte, float* __restrict__ wm) {
  const int d = blockIdx.x * 256 + threadIdx.x;
  const long v0 = (long)blockIdx.y * 256;
  float acc = 0.f;
  for (int v = 0; v < 256; v++) acc += wte[(v0 + v) * DV + d];
  atomicAdd(&wm[d], acc);
}

// colsum[s] = sum over 250 v-block partials (part layout: [vblk][1024])
__global__ void colsum_reduce_k(const float* __restrict__ part, float* __restrict__ cs) {
  const int s = blockIdx.x * 256 + threadIdx.x;
  float acc = 0.f;
  for (int v = 0; v < VV/128; v++) acc += part[(long)v * SV + s];
  cs[s] = acc;
}

// f_k += sum of KC partial slices per batch (slice z = b*KC + c, each (S,D) f32)
__global__ void freduce_k(const float* __restrict__ part, float* __restrict__ f_k, int KC) {
  const long i = ((long)blockIdx.x * 256 + threadIdx.x) * 4;
  const int  b = (int)(i / ((long)SV*DV));
  const long r = i % ((long)SV*DV);
  float4 acc = *(const float4*)(f_k + i);
  for (int c = 0; c < KC; c++) {
    const float4 v = *(const float4*)(part + ((long)(b*KC + c))*SV*DV + r);
    acc.x += v.x; acc.y += v.y; acc.z += v.z; acc.w += v.w;
  }
  *(float4*)(f_k + i) = acc;
}

// Vt = e - (sum of KCX bf16 exw partial slices)/colsum, written transposed (D,S) bf16
__global__ void vt_part_k(const float* __restrict__ e, const bf16* __restrict__ pb,
                          const float* __restrict__ cs, bf16* __restrict__ VtT) {
  __shared__ float t[32][33];
  const int d0 = blockIdx.x * 32, s0 = blockIdx.y * 32;
  const int tx = threadIdx.x, ty = threadIdx.y;
#pragma unroll
  for (int k = 0; k < 4; k++) {
    const int sl = ty + k*8;
    const long off = (long)(s0+sl)*DV + d0+tx;
    float acc = 0.f;
    for (int c = 0; c < KCX; c++) acc += (float)pb[(long)c*SV*DV + off];
    t[sl][tx] = e[off] - acc / cs[s0 + sl];
  }
  __syncthreads();
#pragma unroll
  for (int k = 0; k < 4; k++) {
    const int dl = ty + k*8;
    VtT[(long)(d0+dl)*SV + s0+tx] = (bf16)t[tx][dl];
  }
}

// layer-0 variant: ex_wte is the wte column-mean (uniform softmax), exact algebra
__global__ void vt0_transpose_k(const float* __restrict__ e, const float* __restrict__ wm,
                                bf16* __restrict__ VtT) {
  __shared__ float t[32][33];
  const int d0 = blockIdx.x * 32, s0 = blockIdx.y * 32;
  const int tx = threadIdx.x, ty = threadIdx.y;
  const float mval = wm[d0 + tx] * (1.0f / (float)VV);
#pragma unroll
  for (int k = 0; k < 4; k++) {
    const int sl = ty + k*8;
    t[sl][tx] = e[(long)(s0+sl)*DV + d0+tx] - mval;
  }
  __syncthreads();
#pragma unroll
  for (int k = 0; k < 4; k++) {
    const int dl = ty + k*8;
    VtT[(long)(d0+dl)*SV + s0+tx] = (bf16)t[tx][dl];
  }
}

__global__ void logits_k(const float* __restrict__ obuf, const float* __restrict__ wte,
                         float* __restrict__ out, int V) {
  const int wv = threadIdx.x >> 6, lane = threadIdx.x & 63;
  const int v = blockIdx.x * 4 + wv;
  const int b = blockIdx.y;
  const float* o  = obuf + (long)b * DV;
  const float* wr = wte + (long)v * DV;
  const float4 a  = *(const float4*)(wr + lane*8);
  const float4 c  = *(const float4*)(wr + lane*8 + 4);
  const float4 oa = *(const float4*)(o + lane*8);
  const float4 ob = *(const float4*)(o + lane*8 + 4);
  float dt = a.x*oa.x + a.y*oa.y + a.z*oa.z + a.w*oa.w
           + c.x*ob.x + c.y*ob.y + c.z*ob.z + c.w*ob.w;
#pragma unroll
  for (int off = 32; off > 0; off >>= 1) dt += __shfl_down(dt, off, 64);
  if (lane == 0) out[(long)b * V + v] = dt;
}

// ---------------- m97-style NT MFMA GEMM: C[m,n] = sum_k A[m,k]*B[n,k] ----------------
// 128x128x32 tile, unpadded LDS, global_load_lds width-16 staging.
// EPI: 2=store bf16,
//      3=causal mask * wn[m]*scale -> bf16 (krn build; fully-masked tiles skipped),
//      4=gelu -> bf16,
//      5=exp -> bf16 + per-block partial row-sums into Cf[vblk*SV + s],
//      6=f32 partial-slice store (split-K, slice = b*KC+chunk, stride sCh),
//      7=bf16 partial-slice store (split-K, slice = chunk, stride sCh)
// BSRC: 0 = B bf16 (DMA), 1 = B f32 (VALU convert during staging)
struct GemmArgs {
  const bf16* A; const bf16* B; const float* Bf32;
  float* Cf; bf16* Cb;
  int K, lda, ldb, ldc;
  long sAh, sAb, sBh, sBb, sCh, sCb;
  int Hmod, KC, causal, swap;
  float scale;
};

template<int EPI, int BSRC>
__global__ __launch_bounds__(256)
void gemm_nt(GemmArgs g) {
  __shared__ bf16 As[128][32];
  __shared__ bf16 Bs[128][32];
  const int tid = threadIdx.x;
  const int z = blockIdx.z;
  const int chunk = z % g.KC;
  const int zo = z / g.KC;
  const int h = zo % g.Hmod;
  const int b = zo / g.Hmod;
  int bx = blockIdx.x, by = blockIdx.y;
  if (g.swap) { int t = bx; bx = by; by = t; }
  const int m0 = by * 128;
  const int n0 = bx * 128;
  const long coff = (long)h * g.sCh + (long)b * g.sCb;

  if (EPI == 3 && n0 > m0 + 127) return;  // fully-masked krn tile: never read downstream

  const bf16* A = g.A + (long)h * g.sAh + (long)b * g.sAb;
  const bf16* B = nullptr;
  const float* Bf = nullptr;
  if constexpr (BSRC == 0) B  = g.B + (long)h * g.sBh + (long)b * g.sBb;
  else                     Bf = g.Bf32 + (long)h * g.sBh + (long)b * g.sBb;
  const int lane = tid & 63;
  const int wv = tid >> 6;
  const int wm = (wv >> 1) * 64;
  const int wn = (wv & 1) * 64;
  const int frow = lane & 15;
  const int quad = lane >> 4;
  // DMA staging: wave wv covers rows wv*16 + c*64 .. +15; lane -> (row, 16B chunk)
  const int drow = lane >> 2;
  const int dcol = (lane & 3) * 8;
  // VALU staging (BSRC=1 B path)
  const int sr = tid >> 2;
  const int sc = (tid & 3) * 8;

  const f32x4 fzero = {0.f, 0.f, 0.f, 0.f};
  f32x4 acc[4][4];
#pragma unroll
  for (int i = 0; i < 4; i++)
#pragma unroll
    for (int j = 0; j < 4; j++) acc[i][j] = fzero;

  int k0, klen;
  if (g.causal) { k0 = 0; klen = min(g.K, m0 + 128); }
  else          { klen = g.K / g.KC; k0 = chunk * klen; }

  for (int kt = 0; kt < klen; kt += 32) {
    const int kk = k0 + kt;
#pragma unroll
    for (int c = 0; c < 2; c++) {
      const int rr = c*64 + wv*16;
      lds_dma16(A + (long)(m0 + rr + drow) * g.lda + kk + dcol, &As[rr][0]);
    }
    if constexpr (BSRC == 0) {
#pragma unroll
      for (int c = 0; c < 2; c++) {
        const int rr = c*64 + wv*16;
        lds_dma16(B + (long)(n0 + rr + drow) * g.ldb + kk + dcol, &Bs[rr][0]);
      }
    } else {
#pragma unroll
      for (int i = 0; i < 2; i++) {
        const int r = sr + i*64;
        const float* bp = Bf + (long)(n0 + r) * g.ldb + kk + sc;
        const float4 u0 = *(const float4*)bp;
        const float4 u1 = *(const float4*)(bp + 4);
        bf16x8 t;
        t[0]=(bf16)u0.x; t[1]=(bf16)u0.y; t[2]=(bf16)u0.z; t[3]=(bf16)u0.w;
        t[4]=(bf16)u1.x; t[5]=(bf16)u1.y; t[6]=(bf16)u1.z; t[7]=(bf16)u1.w;
        *(bf16x8*)(&Bs[r][sc]) = t;
      }
    }
    __syncthreads();
    bf16x8 af[4], bfr[4];
#pragma unroll
    for (int i = 0; i < 4; i++)
      af[i] = *(const bf16x8*)(&As[wm + i*16 + frow][quad*8]);
#pragma unroll
    for (int j = 0; j < 4; j++)
      bfr[j] = *(const bf16x8*)(&Bs[wn + j*16 + frow][quad*8]);
#pragma unroll
    for (int i = 0; i < 4; i++)
#pragma unroll
      for (int j = 0; j < 4; j++)
        acc[i][j] = __builtin_amdgcn_mfma_f32_16x16x32_bf16(af[i], bfr[j], acc[i][j], 0, 0, 0);
    __syncthreads();
  }

  const int rb = quad * 4;
  if (EPI == 5) {
    // exp store + per-block partial colsum into Cf[vblk*SV + gm]
    const int vblk = n0 >> 7;
#pragma unroll
    for (int i = 0; i < 4; i++) {
#pragma unroll
      for (int r = 0; r < 4; r++) {
        const int gm = m0 + wm + i*16 + rb + r;
        float rs = 0.f;
#pragma unroll
        for (int j = 0; j < 4; j++) {
          const int gn = n0 + wn + j*16 + frow;
          const float ev = __expf(acc[i][j][r]);
          g.Cb[(long)gm * g.ldc + gn] = (bf16)ev;
          rs += ev;
        }
#pragma unroll
        for (int off = 1; off < 16; off <<= 1)
          rs += __shfl_xor(rs, off, 64);
        if (frow == 0) atomicAdd(g.Cf + (long)vblk * SV + gm, rs);
      }
    }
  } else {
#pragma unroll
    for (int i = 0; i < 4; i++) {
#pragma unroll
      for (int j = 0; j < 4; j++) {
#pragma unroll
        for (int r = 0; r < 4; r++) {
          const int gm = m0 + wm + i*16 + rb + r;
          const int gn = n0 + wn + j*16 + frow;
          const float v = acc[i][j][r];
          if (EPI == 2) {
            g.Cb[coff + (long)gm * g.ldc + gn] = (bf16)v;
          } else if (EPI == 3) {
            const float val = (gn <= gm) ? v * g.scale / (float)(gm + 1) : 0.0f;
            g.Cb[coff + (long)gm * g.ldc + gn] = (bf16)val;
          } else if (EPI == 4) {
            const float ge = 0.5f * v * (1.0f + erff(v * 0.70710678118f));
            g.Cb[coff + (long)gm * g.ldc + gn] = (bf16)ge;
          } else if (EPI == 6) {
            g.Cf[(long)(b*g.KC + chunk) * g.sCh + (long)gm * g.ldc + gn] = v;
          } else if (EPI == 7) {
            g.Cb[(long)chunk * g.sCh + (long)gm * g.ldc + gn] = (bf16)v;
          }
        }
      }
    }
  }
}

// shared tail for each layer: U_rs -> Wo(partial+reduce) -> LN -> MLP(partial+reduce)
static void layer_tail(int il, bf16* krn, bf16* VtT, bf16* U_rs, bf16* Wo_b,
                       float* f_k, bf16* f_k_b, bf16* hbuf, bf16* Gbuf, float* fpart,
                       bf16* w1_b, bf16* w2_b, const float* lnmw, int do_cast,
                       hipStream_t stream) {
  { // U_rs[b][s, h*D+d] = sum_t krn[h,s,t] * Vt[b,t,d]  (causal K-truncation)
    GemmArgs g = {};
    g.A = krn; g.B = VtT; g.Cb = U_rs;
    g.K = SV; g.lda = SV; g.ldb = SV; g.ldc = HV*DV;
    g.sAh = (long)SV*SV; g.sBb = (long)DV*SV;
    g.sCh = DV; g.sCb = (long)SV*HV*DV;
    g.Hmod = HV; g.KC = 1; g.causal = 1;
    gemm_nt<2,0><<<dim3(DV/128, SV/128, BV*HV), 256, 0, stream>>>(g);
  }
  { // fpart[b*8+c] = partial of U_rs @ Wo[il]^T  (split-K=8, plain stores)
    GemmArgs g = {};
    g.A = U_rs; g.B = Wo_b + (long)il*DV*HV*DV; g.Cf = fpart;
    g.K = HV*DV; g.lda = HV*DV; g.ldb = HV*DV; g.ldc = DV;
    g.sAb = (long)SV*HV*DV; g.sCh = (long)SV*DV;
    g.Hmod = 1; g.KC = 8; g.causal = 0;
    gemm_nt<6,0><<<dim3(DV/128, SV/128, BV*8), 256, 0, stream>>>(g);
  }
  freduce_k<<<dim3(BV*SV*DV/4/256), 256, 0, stream>>>(fpart, f_k, 8);
  rows_ln_bf16_k<<<dim3(BV*SV/4), 256, 0, stream>>>(f_k, lnmw, hbuf, BV*SV);
  { // Gbuf = gelu(h @ w1^T)
    GemmArgs g = {};
    g.A = hbuf; g.B = w1_b; g.Cb = Gbuf;
    g.K = DV; g.lda = DV; g.ldb = DV; g.ldc = DFFV;
    g.sAb = (long)SV*DV; g.sCb = (long)SV*DFFV;
    g.Hmod = 1; g.KC = 1; g.causal = 0;
    gemm_nt<4,0><<<dim3(DFFV/128, SV/128, BV), 256, 0, stream>>>(g);
  }
  { // fpart[b*8+c] = partial of Gbuf @ w2^T  (split-K=8, plain stores)
    GemmArgs g = {};
    g.A = Gbuf; g.B = w2_b; g.Cf = fpart;
    g.K = DFFV; g.lda = DFFV; g.ldb = DFFV; g.ldc = DV;
    g.sAb = (long)SV*DFFV; g.sCh = (long)SV*DV;
    g.Hmod = 1; g.KC = 8; g.causal = 0;
    gemm_nt<6,0><<<dim3(DV/128, SV/128, BV*8), 256, 0, stream>>>(g);
  }
  freduce_k<<<dim3(BV*SV*DV/4/256), 256, 0, stream>>>(fpart, f_k, 8);
  if (do_cast)
    cast_f2b_k<<<dim3((BV*SV*DV/4+255)/256), 256, 0, stream>>>(f_k, f_k_b, (long)BV*SV*DV);
}

extern "C" void kernel_launch(void* const* d_in, const int* in_sizes, int n_in,
                              void* d_out, int out_size, void* d_ws, size_t ws_size,
                              hipStream_t stream) {
  const int*   x    = (const int*)d_in[0];
  const float* wte  = (const float*)d_in[1];
  const float* wpe  = (const float*)d_in[2];
  const float* lnew = (const float*)d_in[3];
  const float* lnpw = (const float*)d_in[4];
  const float* lnfw = (const float*)d_in[5];
  const float* lnmw = (const float*)d_in[6];
  const float* Wq   = (const float*)d_in[7];
  const float* Wk   = (const float*)d_in[8];
  const float* Wo   = (const float*)d_in[9];
  const float* w1   = (const float*)d_in[10];
  const float* w2   = (const float*)d_in[11];
  float* out = (float*)d_out;
  (void)in_sizes; (void)n_in; (void)out_size; (void)ws_size;

  char* p = (char*)d_ws;
  auto alloc = [&](size_t bytes) -> void* {
    void* r = (void*)p;
    p += (bytes + 255) & ~(size_t)255;
    return r;
  };
  // persistent buffers (~150 MB)
  float* e      = (float*)alloc((size_t)BV*SV*DV*4);
  float* pn     = (float*)alloc((size_t)(SV+1)*DV*4);
  bf16*  wteT_b = (bf16*)alloc((size_t)DV*VV*2);
  bf16*  wte_b  = (bf16*)alloc((size_t)VV*DV*2);
  bf16*  krn    = (bf16*)alloc((size_t)HV*SV*SV*2);
  bf16*  Wo_b   = (bf16*)alloc((size_t)NLV*DV*HV*DV*2);
  bf16*  w1_b   = (bf16*)alloc((size_t)DFFV*DV*2);
  bf16*  w2_b   = (bf16*)alloc((size_t)DV*DFFV*2);
  float* f_k    = (float*)alloc((size_t)BV*SV*DV*4);
  bf16*  f_k_b  = (bf16*)alloc((size_t)BV*SV*DV*2);
  bf16*  expart = (bf16*)alloc((size_t)KCX*SV*DV*2);     // 20 MB exw bf16 partial slices
  bf16*  VtT    = (bf16*)alloc((size_t)BV*DV*SV*2);
  bf16*  hbuf   = (bf16*)alloc((size_t)BV*SV*DV*2);
  float* colsum = (float*)alloc((size_t)SV*4);
  float* part   = (float*)alloc((size_t)(VV/128)*SV*4);   // 1 MB partial colsums
  float* obuf   = (float*)alloc((size_t)BV*DV*4);
  float* wmean  = (float*)alloc((size_t)DV*4);
  // arena (65.5 MB), time-sliced: {Qh,Kh} -> tail{U_rs,Gbuf,fpart} -> PT -> tail
  char*  arena  = (char*)alloc((size_t)SV*VV*2);
  bf16*  Qh     = (bf16*)arena;
  bf16*  Kh     = (bf16*)(arena + (size_t)HV*SV*DV*2);
  bf16*  PT     = (bf16*)arena;                            // (S,V) unnormalized probs
  bf16*  U_rs   = (bf16*)arena;                            // [0, 16.8 MB)
  bf16*  Gbuf   = (bf16*)(arena + (size_t)BV*SV*HV*DV*2);  // [16.8, 25.2 MB)
  float* fpart  = (float*)(arena + (size_t)BV*SV*HV*DV*2 + (size_t)BV*SV*DFFV*2); // [25.2, 58.7)

  // ---- prologue ----
  hipMemsetAsync(f_k,   0, (size_t)BV*SV*DV*4, stream);
  hipMemsetAsync(f_k_b, 0, (size_t)BV*SV*DV*2, stream);
  hipMemsetAsync(wmean, 0, (size_t)DV*4, stream);
  wmean_k<<<dim3(DV/256, VV/256), 256, 0, stream>>>(wte, wmean);
  transpose_f2b_k<<<dim3(DV/32, VV/32), dim3(32,8), 0, stream>>>(wte, wteT_b, VV, DV);
  cast_f2b_k<<<dim3((VV*DV/4+255)/256), 256, 0, stream>>>(wte, wte_b, (long)VV*DV);
  cast_f2b_k<<<dim3((NLV*DV*HV*DV/4+255)/256), 256, 0, stream>>>(Wo, Wo_b, (long)NLV*DV*HV*DV);
  cast_f2b_k<<<dim3((DFFV*DV/4+255)/256), 256, 0, stream>>>(w1, w1_b, (long)DFFV*DV);
  cast_f2b_k<<<dim3((DV*DFFV/4+255)/256), 256, 0, stream>>>(w2, w2_b, (long)DV*DFFV);
  embed_ln_k<<<dim3(BV*SV/4), 256, 0, stream>>>(x, wte, lnew, e, BV*SV);
  rows_ln_f32_k<<<dim3((SV+1+3)/4), 256, 0, stream>>>(wpe, lnpw, pn, SV+1);
  qk_prep_k<<<dim3(SV, HV), 128, 0, stream>>>(pn, Wq, Wk, Qh, Kh);

  { // krn[h,s,t] = mask(t<=s) * (Q.K)/sqrt(D) * wn[s]  -> bf16 (masked tiles skipped)
    GemmArgs g = {};
    g.A = Qh; g.B = Kh; g.Cb = krn;
    g.K = DV; g.lda = DV; g.ldb = DV; g.ldc = SV;
    g.sAh = (long)SV*DV; g.sBh = (long)SV*DV; g.sCh = (long)SV*SV;
    g.Hmod = HV; g.KC = 1; g.causal = 0;
    g.scale = 0.044194173824159216f;  // 1/sqrt(512)
    gemm_nt<3,0><<<dim3(SV/128, SV/128, HV), 256, 0, stream>>>(g);
  }

  // ---- layer 0: f_k==0 => R uniform => ex_wte/sumR == mean_v(wte) (exact) ----
  for (int b = 0; b < BV; b++)
    vt0_transpose_k<<<dim3(DV/32, SV/32), dim3(32,8), 0, stream>>>(
        e + (long)b*SV*DV, wmean, VtT + (long)b*DV*SV);
  layer_tail(0, krn, VtT, U_rs, Wo_b, f_k, f_k_b, hbuf, Gbuf, fpart,
             w1_b, w2_b, lnmw, 1, stream);

  // ---- layer 1: PT = exp(f_k@wte^T); per-v Z and max-shift drop out of exw/colsum ----
  for (int b = 0; b < BV; b++) {
    hipMemsetAsync(part, 0, (size_t)(VV/128)*SV*4, stream);
    { // PT(S,V) = exp(logits), fused partial colsum into part
      GemmArgs g = {};
      g.A = f_k_b + (long)b*SV*DV; g.B = wte_b; g.Cb = PT; g.Cf = part;
      g.K = DV; g.lda = DV; g.ldb = DV; g.ldc = VV;
      g.Hmod = 1; g.KC = 1; g.causal = 0; g.swap = 1;
      gemm_nt<5,0><<<dim3(SV/128, VV/128, 1), 256, 0, stream>>>(g);
    }
    colsum_reduce_k<<<dim3(SV/256), 256, 0, stream>>>(part, colsum);
    { // expart[c] = partial of P'^T @ wte  (split-K=20 over V, plain bf16 stores)
      GemmArgs g = {};
      g.A = PT; g.B = wteT_b; g.Cb = expart;
      g.K = VV; g.lda = VV; g.ldb = VV; g.ldc = DV;
      g.sCh = (long)SV*DV;
      g.Hmod = 1; g.KC = KCX; g.causal = 0;
      gemm_nt<7,0><<<dim3(DV/128, SV/128, KCX), 256, 0, stream>>>(g);
    }
    vt_part_k<<<dim3(DV/32, SV/32), dim3(32,8), 0, stream>>>(
        e + (long)b*SV*DV, expart, colsum, VtT + (long)b*DV*SV);
  }
  layer_tail(1, krn, VtT, U_rs, Wo_b, f_k, f_k_b, hbuf, Gbuf, fpart,
             w1_b, w2_b, lnmw, 0, stream);

  final_ln_k<<<1, 256, 0, stream>>>(f_k, lnfw, obuf);
  logits_k<<<dim3(VV/4, BV), 256, 0, stream>>>(obuf, wte, out, VV);
}